// Round 2
// baseline (269.157 us; speedup 1.0000x reference)
//
#include <hip/hip_runtime.h>
#include <hip/hip_bf16.h>

// ---------------------------------------------------------------------------
// TransformerPlanner: algebra-collapsed fused implementation, round 2.
// R2 change: GE 16->8 (M=24), LDS 64KB->31.9KB => 5 WGs/CU (20 waves),
// all phases parallelized (P2: 256 thr w/ 4-lane shuffle softmax; LN phases:
// 192 thr, 8 lanes/row shuffle-reduced), tables/coords read direct from
// global (L1), one fewer barrier. MFMA garbage rows clamped+masked.
// ---------------------------------------------------------------------------

typedef __bf16 bf16x8 __attribute__((ext_vector_type(8)));
typedef float  f32x4  __attribute__((ext_vector_type(4)));
static_assert(sizeof(bf16x8) == 16, "bf16x8 must be 16B");

__device__ __forceinline__ unsigned short f2b(float x) {
  __bf16 h = (__bf16)x;
  return __builtin_bit_cast(unsigned short, h);
}
__device__ __forceinline__ float b2f(unsigned short u) {
  return (float)__builtin_bit_cast(__bf16, u);
}
__device__ __forceinline__ unsigned pack2(float a, float b) {
  return (unsigned)f2b(a) | ((unsigned)f2b(b) << 16);
}
__device__ __forceinline__ float dot4(float4 a, float4 b) {
  return a.x*b.x + a.y*b.y + a.z*b.z + a.w*b.w;
}
__device__ __forceinline__ f32x4 mfma16(bf16x8 a, bf16x8 b, f32x4 c) {
  return __builtin_amdgcn_mfma_f32_16x16x32_bf16(a, b, c, 0, 0, 0);
}

// ---- workspace layout (byte offsets into d_ws) ----
#define WS_OM    0          // ushort[128*192]
#define WS_FC1   49152      // ushort[256*128]
#define WS_FC2   114688     // ushort[128*256]
#define WS_VB    180224     // float[20*128]
#define WS_VU    190464
#define WS_VW    190976
#define WS_VC    191488
#define WS_QN    192000     // float[3*128]
#define WS_SB    193536     // float[480]
#define WS_SU    195456     // float[72]
#define WS_SCAL  195744     // float[3]
#define WS_SUB   195756     // float[20]
#define WS_SWB   195836     // float[20]
#define WS_SBB   195916     // float[20]

// ---------------------------------------------------------------------------
__device__ float mean128(float v, volatile float* red) {
  #pragma unroll
  for (int o = 32; o; o >>= 1) v += __shfl_down(v, o, 64);
  __syncthreads();
  if ((threadIdx.x & 63) == 0) red[threadIdx.x >> 6] = v;
  __syncthreads();
  return (red[0] + red[1]) * (1.0f / 128.0f);
}

__global__ void k_tables(
    const float* __restrict__ coord_w, const float* __restrict__ coord_b,
    const float* __restrict__ pos_emb, const float* __restrict__ side_emb,
    const float* __restrict__ query_emb,
    const float* __restrict__ tln_g, const float* __restrict__ tln_b,
    const float* __restrict__ qln_g, const float* __restrict__ qln_b,
    const float* __restrict__ ipw, const float* __restrict__ ipb,
    char* __restrict__ ws)
{
  __shared__ float red[2];
  __shared__ float qn[3][128];
  __shared__ float qmat[3][128];
  __shared__ float vecA[128];
  __shared__ float vecB[128];
  __shared__ float vecC[128];
  __shared__ float kuA[128];
  __shared__ float kwA[128];
  __shared__ float kcA[128];
  const int d = threadIdx.x;
  const int t = blockIdx.x;

  float u  = coord_w[d*2+0];
  float w2 = coord_w[d*2+1];
  float g  = tln_g[d];
  float mu = mean128(u,  red);
  float mw = mean128(w2, red);
  float uh = u - mu, wh = w2 - mw;

  #pragma unroll
  for (int w = 0; w < 3; w++) {
    float qe = query_emb[w*128 + d];
    float m  = mean128(qe, red);
    float m2 = mean128(qe*qe, red);
    float var = m2 - m*m;
    qn[w][d] = (qe - m) * rsqrtf(var + 1e-5f) * qln_g[d] + qln_b[d];
  }
  __syncthreads();
  {
    const float* wqr = ipw + d*128;
    float a0 = 0, a1 = 0, a2 = 0;
    for (int k4 = 0; k4 < 32; k4++) {
      float4 wv4 = *(const float4*)&wqr[k4*4];
      a0 += dot4(wv4, *(const float4*)&qn[0][k4*4]);
      a1 += dot4(wv4, *(const float4*)&qn[1][k4*4]);
      a2 += dot4(wv4, *(const float4*)&qn[2][k4*4]);
    }
    float bq = ipb[d];
    qmat[0][d] = a0 + bq; qmat[1][d] = a1 + bq; qmat[2][d] = a2 + bq;
  }
  __syncthreads();

  if (t < 20) {
    float base = coord_b[d] + pos_emb[(t % 10)*128 + d] + side_emb[(t < 10 ? 0 : 1)*128 + d];
    float mb = mean128(base, red);
    float bh = base - mb;
    float sub = mean128(uh*bh, red);
    float swb = mean128(wh*bh, red);
    float sbb = mean128(bh*bh, red);
    if (d == 0) {
      ((float*)(ws + WS_SUB))[t] = sub;
      ((float*)(ws + WS_SWB))[t] = swb;
      ((float*)(ws + WS_SBB))[t] = sbb;
    }
    vecA[d] = bh * g;
    __syncthreads();
    const float* wkr = ipw + (128 + d)*128;
    const float* wvr = ipw + (256 + d)*128;
    float kb = 0, vb = 0;
    for (int k4 = 0; k4 < 32; k4++) {
      float4 a4 = *(const float4*)&vecA[k4*4];
      kb += dot4(*(const float4*)&wkr[k4*4], a4);
      vb += dot4(*(const float4*)&wvr[k4*4], a4);
    }
    kuA[d] = kb;
    ((float*)(ws + WS_VB))[t*128 + d] = vb;
    __syncthreads();
    if (d < 24) {
      int w = d / 8, h = d % 8;
      float s = 0;
      #pragma unroll
      for (int dl = 0; dl < 16; dl++) s += qmat[w][h*16 + dl] * kuA[h*16 + dl];
      ((float*)(ws + WS_SB))[(w*8 + h)*20 + t] = 0.25f * s;
    }
  } else {
    float suu = mean128(uh*uh, red);
    float sww = mean128(wh*wh, red);
    float suw = mean128(uh*wh, red);
    if (d == 0) {
      float* sc = (float*)(ws + WS_SCAL);
      sc[0] = suu; sc[1] = sww; sc[2] = suw;
    }
    vecA[d] = uh * g; vecB[d] = wh * g; vecC[d] = tln_b[d];
    __syncthreads();
    const float* wkr = ipw + (128 + d)*128;
    const float* wvr = ipw + (256 + d)*128;
    float ku = 0, kw = 0, kc = 0, vu = 0, vw = 0, vc = 0;
    for (int k4 = 0; k4 < 32; k4++) {
      float4 a4 = *(const float4*)&vecA[k4*4];
      float4 b4 = *(const float4*)&vecB[k4*4];
      float4 c4 = *(const float4*)&vecC[k4*4];
      float4 kv = *(const float4*)&wkr[k4*4];
      float4 vv = *(const float4*)&wvr[k4*4];
      ku += dot4(kv, a4); kw += dot4(kv, b4); kc += dot4(kv, c4);
      vu += dot4(vv, a4); vw += dot4(vv, b4); vc += dot4(vv, c4);
    }
    kc += ipb[128 + d]; vc += ipb[256 + d];
    ((float*)(ws + WS_VU))[d] = vu;
    ((float*)(ws + WS_VW))[d] = vw;
    ((float*)(ws + WS_VC))[d] = vc;
    kuA[d] = ku; kwA[d] = kw; kcA[d] = kc;
    float* qnw = (float*)(ws + WS_QN);
    qnw[0*128 + d] = qn[0][d]; qnw[1*128 + d] = qn[1][d]; qnw[2*128 + d] = qn[2][d];
    __syncthreads();
    if (d < 24) {
      int w = d / 8, h = d % 8;
      float su = 0, sw = 0, sc2 = 0;
      #pragma unroll
      for (int dl = 0; dl < 16; dl++) {
        float q = qmat[w][h*16 + dl];
        su  += q * kuA[h*16 + dl];
        sw  += q * kwA[h*16 + dl];
        sc2 += q * kcA[h*16 + dl];
      }
      float* o = (float*)(ws + WS_SU);
      o[ 0 + w*8 + h] = 0.25f * su;
      o[24 + w*8 + h] = 0.25f * sw;
      o[48 + w*8 + h] = 0.25f * sc2;
    }
  }
}

__global__ void k_build(
    const float* __restrict__ opw, const float* __restrict__ opb,
    const float* __restrict__ f1w, const float* __restrict__ f2w,
    char* __restrict__ ws)
{
  const int b = blockIdx.x, tid = threadIdx.x;
  if (b < 128) {
    __shared__ float Or[128];
    if (tid < 128) Or[tid] = opw[b*128 + tid];
    __syncthreads();
    if (tid < 192) {
      const float* VB = (const float*)(ws + WS_VB);
      const float* VU = (const float*)(ws + WS_VU);
      const float* VW = (const float*)(ws + WS_VW);
      const float* VC = (const float*)(ws + WS_VC);
      float val = 0.0f;
      if (tid < 160) {
        int h = tid / 20, tt = tid % 20;
        #pragma unroll
        for (int dl = 0; dl < 16; dl++) val += Or[h*16 + dl] * VB[tt*128 + h*16 + dl];
      } else if (tid < 168) {
        int h = tid - 160;
        #pragma unroll
        for (int dl = 0; dl < 16; dl++) val += Or[h*16 + dl] * VU[h*16 + dl];
      } else if (tid < 176) {
        int h = tid - 168;
        #pragma unroll
        for (int dl = 0; dl < 16; dl++) val += Or[h*16 + dl] * VW[h*16 + dl];
      } else if (tid == 176) {
        for (int d = 0; d < 128; d++) val += Or[d] * VC[d];
        val += opb[b];
      } else {
        val = 0.0f;
      }
      ((unsigned short*)(ws + WS_OM))[b*192 + tid] = f2b(val);
    }
  } else if (b < 144) {
    unsigned short* dst = (unsigned short*)(ws + WS_FC1);
    int i0 = (b - 128)*2048;
    #pragma unroll
    for (int j = 0; j < 8; j++) { int i = i0 + j*256 + tid; dst[i] = f2b(f1w[i]); }
  } else {
    unsigned short* dst = (unsigned short*)(ws + WS_FC2);
    int i0 = (b - 144)*2048;
    #pragma unroll
    for (int j = 0; j < 8; j++) { int i = i0 + j*256 + tid; dst[i] = f2b(f2w[i]); }
  }
}

// ---------------------------------------------------------------------------
// Main fused kernel: 8 batch elements per WG (M = 24 rows), 256 threads.
// LDS 31872 B -> 5 WGs/CU (20 waves).
#define GE 8
#define MR 24

__global__ __launch_bounds__(256, 5) void k_main(
    const float* __restrict__ tl, const float* __restrict__ tr,
    const float* __restrict__ f1b, const float* __restrict__ f2b_,
    const float* __restrict__ pag, const float* __restrict__ pab,
    const float* __restrict__ pfg, const float* __restrict__ pfb,
    const float* __restrict__ hw, const float* __restrict__ hb,
    const char* __restrict__ ws, float* __restrict__ out)
{
  __shared__ __align__(16) char smem[31872];
  float* S1 = (float*)smem;                              // 24 x 132 f32 (attn_out / h2)
  unsigned short* Z  = (unsigned short*)(smem + 12672);  // 24 x 200 bf16 (K=192 used)
  unsigned short* h1 = (unsigned short*)(smem + 12672);  // 24 x 264 bf16 (aliases Z)
  unsigned short* X  = (unsigned short*)(smem + 25344);  // 24 x 136 bf16

  const unsigned short* OM = (const unsigned short*)(ws + WS_OM);
  const unsigned short* W1 = (const unsigned short*)(ws + WS_FC1);
  const unsigned short* W2 = (const unsigned short*)(ws + WS_FC2);
  const float* QN   = (const float*)(ws + WS_QN);
  const float* SBwf = (const float*)(ws + WS_SB);
  const float* SUwf = (const float*)(ws + WS_SU);
  const float* SCAL = (const float*)(ws + WS_SCAL);
  const float* SUB  = (const float*)(ws + WS_SUB);
  const float* SWB  = (const float*)(ws + WS_SWB);
  const float* SBB  = (const float*)(ws + WS_SBB);

  const int tid  = threadIdx.x;
  const int wg   = blockIdx.x;
  const int lane = tid & 63;
  const int wv   = tid >> 6;
  const int quad = lane >> 4;

  // ---- P2: rs + scores + softmax + P,Q -> Z (all 256 threads) ----
  {
    if (tid < MR) {  // constant tail of Z rows: [176]=1.0, [177..191]=0
      *(uint4*)(Z + tid*200 + 176) = uint4{0x3F80u, 0u, 0u, 0u};
      *(uint4*)(Z + tid*200 + 184) = uint4{0u, 0u, 0u, 0u};
    }
    int e = tid >> 5, h = (tid >> 2) & 7, q = tid & 3;
    const float* cb = (q < 2 ? tl : tr) + (wg*GE + e)*20 + (q & 1)*10;
    float suu = SCAL[0], sww = SCAL[1], suw2 = 2.0f*SCAL[2];
    float xa[5], ya[5], ra[5];
    #pragma unroll
    for (int j = 0; j < 5; j++) {
      float2 c = *(const float2*)(cb + 2*j);
      int t = q*5 + j;
      float var = fmaf(suu, c.x*c.x, fmaf(sww, c.y*c.y, suw2*(c.x*c.y)))
                + 2.0f*SUB[t]*c.x + 2.0f*SWB[t]*c.y + SBB[t];
      float rv = rsqrtf(var + 1e-5f);
      xa[j] = c.x*rv; ya[j] = c.y*rv; ra[j] = rv;
    }
    unsigned short* Zr0 = Z + e*3*200;
    #pragma unroll
    for (int w = 0; w < 3; w++) {
      float su = SUwf[w*8 + h], sw = SUwf[24 + w*8 + h], sc = SUwf[48 + w*8 + h];
      const float* sb = SBwf + (w*8 + h)*20 + q*5;
      float s[5];
      float m = -1e30f;
      #pragma unroll
      for (int j = 0; j < 5; j++) {
        s[j] = fmaf(xa[j], su, fmaf(ya[j], sw, fmaf(ra[j], sb[j], sc)));
        m = fmaxf(m, s[j]);
      }
      m = fmaxf(m, __shfl_xor(m, 1));
      m = fmaxf(m, __shfl_xor(m, 2));
      float sum = 0, P = 0, Q = 0;
      #pragma unroll
      for (int j = 0; j < 5; j++) {
        float p = __expf(s[j] - m);
        s[j] = p; sum += p;
        P = fmaf(p, xa[j], P); Q = fmaf(p, ya[j], Q);
      }
      sum += __shfl_xor(sum, 1); sum += __shfl_xor(sum, 2);
      P   += __shfl_xor(P, 1);   P   += __shfl_xor(P, 2);
      Q   += __shfl_xor(Q, 1);   Q   += __shfl_xor(Q, 2);
      float inv = 1.0f / sum;
      unsigned short* Zr = Zr0 + w*200;
      #pragma unroll
      for (int j = 0; j < 5; j++) Zr[h*20 + q*5 + j] = f2b(s[j]*ra[j]*inv);
      if (q == 0) { Zr[160 + h] = f2b(P*inv); Zr[168 + h] = f2b(Q*inv); }
    }
  }
  __syncthreads();

  // ---- P3: GEMM1  attn_out(24x128) = Z(24x192) @ OM^T ----
  {
    int nbase = wv * 32;
    int n0 = nbase + (lane & 15), n1 = n0 + 16;
    int r0c = lane & 15;
    int r1c = min(16 + (lane & 15), 23);   // clamp: rows 24..31 duplicate 23 (in-bounds)
    f32x4 acc[2][2];
    #pragma unroll
    for (int mt = 0; mt < 2; mt++)
      #pragma unroll
      for (int nt = 0; nt < 2; nt++) acc[mt][nt] = (f32x4){0.f,0.f,0.f,0.f};
    #pragma unroll
    for (int kt = 0; kt < 6; kt++) {
      int k = kt*32 + quad*8;
      bf16x8 Bf0 = *(const bf16x8*)(OM + n0*192 + k);
      bf16x8 Bf1 = *(const bf16x8*)(OM + n1*192 + k);
      bf16x8 Af0 = *(const bf16x8*)(Z + r0c*200 + k);
      bf16x8 Af1 = *(const bf16x8*)(Z + r1c*200 + k);
      acc[0][0] = mfma16(Af0, Bf0, acc[0][0]);
      acc[0][1] = mfma16(Af0, Bf1, acc[0][1]);
      acc[1][0] = mfma16(Af1, Bf0, acc[1][0]);
      acc[1][1] = mfma16(Af1, Bf1, acc[1][1]);
    }
    #pragma unroll
    for (int mt = 0; mt < 2; mt++) {
      if (mt == 1 && quad >= 2) break;     // rows >= 24 are garbage; don't store
      #pragma unroll
      for (int nt = 0; nt < 2; nt++) {
        int col = nbase + nt*16 + (lane & 15);
        int r0  = mt*16 + quad*4;
        #pragma unroll
        for (int j = 0; j < 4; j++) S1[(r0 + j)*132 + col] = acc[mt][nt][j];
      }
    }
  }
  __syncthreads();

  // ---- P4: x = LN(queries_n + attn_out) -> X bf16  (192 thr, 8/row) ----
  if (tid < 192) {
    int r = tid >> 3, p = tid & 7, w = r % 3;
    float4 v[4];
    #pragma unroll
    for (int j = 0; j < 4; j++) {          // rotated reads break bank aliasing
      int i = (j + p) & 3;
      v[i] = *(float4*)&S1[r*132 + p*16 + i*4];
    }
    const float* qrow = QN + w*128 + p*16;
    float s1 = 0, s2 = 0;
    #pragma unroll
    for (int i = 0; i < 4; i++) {
      float4 q4 = *(const float4*)(qrow + i*4);
      v[i].x += q4.x; v[i].y += q4.y; v[i].z += q4.z; v[i].w += q4.w;
      s1 += v[i].x + v[i].y + v[i].z + v[i].w;
      s2 += v[i].x*v[i].x + v[i].y*v[i].y + v[i].z*v[i].z + v[i].w*v[i].w;
    }
    #pragma unroll
    for (int o = 1; o < 8; o <<= 1) { s1 += __shfl_xor(s1, o); s2 += __shfl_xor(s2, o); }
    float m  = s1 * (1.0f/128.0f);
    float sc = rsqrtf(s2 * (1.0f/128.0f) - m*m + 1e-5f);
    unsigned pk[8];
    #pragma unroll
    for (int i = 0; i < 4; i++) {
      float4 g4 = *(const float4*)(pag + p*16 + i*4);
      float4 b4 = *(const float4*)(pab + p*16 + i*4);
      float a0 = (v[i].x - m)*sc*g4.x + b4.x;
      float a1 = (v[i].y - m)*sc*g4.y + b4.y;
      float a2 = (v[i].z - m)*sc*g4.z + b4.z;
      float a3 = (v[i].w - m)*sc*g4.w + b4.w;
      pk[i*2]   = pack2(a0, a1);
      pk[i*2+1] = pack2(a2, a3);
    }
    *(uint4*)&X[r*136 + p*16]     = uint4{pk[0], pk[1], pk[2], pk[3]};
    *(uint4*)&X[r*136 + p*16 + 8] = uint4{pk[4], pk[5], pk[6], pk[7]};
  }
  __syncthreads();

  // ---- P5: fc1 + relu -> h1 bf16 (24x256) ----
  {
    int nbase = wv * 64;
    int r0c = lane & 15;
    int r1c = min(16 + (lane & 15), 23);
    f32x4 acc[2][4];
    #pragma unroll
    for (int mt = 0; mt < 2; mt++)
      #pragma unroll
      for (int nt = 0; nt < 4; nt++) acc[mt][nt] = (f32x4){0.f,0.f,0.f,0.f};
    #pragma unroll
    for (int kt = 0; kt < 4; kt++) {
      int k = kt*32 + quad*8;
      bf16x8 Af0 = *(const bf16x8*)(X + r0c*136 + k);
      bf16x8 Af1 = *(const bf16x8*)(X + r1c*136 + k);
      #pragma unroll
      for (int nt = 0; nt < 4; nt++) {
        bf16x8 Bf = *(const bf16x8*)(W1 + (nbase + nt*16 + (lane & 15))*128 + k);
        acc[0][nt] = mfma16(Af0, Bf, acc[0][nt]);
        acc[1][nt] = mfma16(Af1, Bf, acc[1][nt]);
      }
    }
    #pragma unroll
    for (int nt = 0; nt < 4; nt++) {
      int col = nbase + nt*16 + (lane & 15);
      float bb = f1b[col];
      #pragma unroll
      for (int mt = 0; mt < 2; mt++) {
        if (mt == 1 && quad >= 2) break;
        int r0 = mt*16 + quad*4;
        #pragma unroll
        for (int j = 0; j < 4; j++)
          h1[(r0 + j)*264 + col] = f2b(fmaxf(acc[mt][nt][j] + bb, 0.0f));
      }
    }
  }
  __syncthreads();

  // ---- P6: h2 = h1 @ fc2^T + b -> S1 f32 ----
  {
    int nbase = wv * 32;
    int n0 = nbase + (lane & 15), n1 = n0 + 16;
    int r0c = lane & 15;
    int r1c = min(16 + (lane & 15), 23);
    f32x4 acc[2][2];
    #pragma unroll
    for (int mt = 0; mt < 2; mt++)
      #pragma unroll
      for (int nt = 0; nt < 2; nt++) acc[mt][nt] = (f32x4){0.f,0.f,0.f,0.f};
    #pragma unroll
    for (int kt = 0; kt < 8; kt++) {
      int k = kt*32 + quad*8;
      bf16x8 Bf0 = *(const bf16x8*)(W2 + n0*256 + k);
      bf16x8 Bf1 = *(const bf16x8*)(W2 + n1*256 + k);
      bf16x8 Af0 = *(const bf16x8*)(h1 + r0c*264 + k);
      bf16x8 Af1 = *(const bf16x8*)(h1 + r1c*264 + k);
      acc[0][0] = mfma16(Af0, Bf0, acc[0][0]);
      acc[0][1] = mfma16(Af0, Bf1, acc[0][1]);
      acc[1][0] = mfma16(Af1, Bf0, acc[1][0]);
      acc[1][1] = mfma16(Af1, Bf1, acc[1][1]);
    }
    #pragma unroll
    for (int mt = 0; mt < 2; mt++) {
      if (mt == 1 && quad >= 2) break;
      #pragma unroll
      for (int nt = 0; nt < 2; nt++) {
        int col = nbase + nt*16 + (lane & 15);
        float bb = f2b_[col];
        int r0 = mt*16 + quad*4;
        #pragma unroll
        for (int j = 0; j < 4; j++) S1[(r0 + j)*132 + col] = acc[mt][nt][j] + bb;
      }
    }
  }
  __syncthreads();

  // ---- P7: x2 = LN(x + h2); out = x2 @ head^T + hb  (192 thr, 8/row) ----
  if (tid < 192) {
    int r = tid >> 3, p = tid & 7;
    int e = r / 3, w = r % 3;
    float4 v[4];
    #pragma unroll
    for (int j = 0; j < 4; j++) {
      int i = (j + p) & 3;
      v[i] = *(float4*)&S1[r*132 + p*16 + i*4];
    }
    uint4 u0 = *(const uint4*)&X[r*136 + p*16];
    uint4 u1 = *(const uint4*)&X[r*136 + p*16 + 8];
    float xb[16];
    xb[0]=b2f(u0.x&0xffff); xb[1]=b2f(u0.x>>16); xb[2]=b2f(u0.y&0xffff); xb[3]=b2f(u0.y>>16);
    xb[4]=b2f(u0.z&0xffff); xb[5]=b2f(u0.z>>16); xb[6]=b2f(u0.w&0xffff); xb[7]=b2f(u0.w>>16);
    xb[8]=b2f(u1.x&0xffff); xb[9]=b2f(u1.x>>16); xb[10]=b2f(u1.y&0xffff); xb[11]=b2f(u1.y>>16);
    xb[12]=b2f(u1.z&0xffff); xb[13]=b2f(u1.z>>16); xb[14]=b2f(u1.w&0xffff); xb[15]=b2f(u1.w>>16);
    float s1 = 0, s2 = 0;
    #pragma unroll
    for (int i = 0; i < 4; i++) {
      v[i].x += xb[i*4+0]; v[i].y += xb[i*4+1]; v[i].z += xb[i*4+2]; v[i].w += xb[i*4+3];
      s1 += v[i].x + v[i].y + v[i].z + v[i].w;
      s2 += v[i].x*v[i].x + v[i].y*v[i].y + v[i].z*v[i].z + v[i].w*v[i].w;
    }
    #pragma unroll
    for (int o = 1; o < 8; o <<= 1) { s1 += __shfl_xor(s1, o); s2 += __shfl_xor(s2, o); }
    float m  = s1 * (1.0f/128.0f);
    float sc = rsqrtf(s2 * (1.0f/128.0f) - m*m + 1e-5f);
    float o0 = 0, o1 = 0;
    #pragma unroll
    for (int i = 0; i < 4; i++) {
      float4 g4 = *(const float4*)(pfg + p*16 + i*4);
      float4 b4 = *(const float4*)(pfb + p*16 + i*4);
      float4 h0 = *(const float4*)(hw + p*16 + i*4);
      float4 h8 = *(const float4*)(hw + 128 + p*16 + i*4);
      float x0 = (v[i].x - m)*sc*g4.x + b4.x;
      float x1 = (v[i].y - m)*sc*g4.y + b4.y;
      float x2 = (v[i].z - m)*sc*g4.z + b4.z;
      float x3 = (v[i].w - m)*sc*g4.w + b4.w;
      o0 = fmaf(x0,h0.x, fmaf(x1,h0.y, fmaf(x2,h0.z, fmaf(x3,h0.w, o0))));
      o1 = fmaf(x0,h8.x, fmaf(x1,h8.y, fmaf(x2,h8.z, fmaf(x3,h8.w, o1))));
    }
    #pragma unroll
    for (int o = 1; o < 8; o <<= 1) { o0 += __shfl_xor(o0, o); o1 += __shfl_xor(o1, o); }
    if (p == 0) {
      int gi = ((wg*GE + e)*3 + w)*2;
      out[gi]     = o0 + hb[0];
      out[gi + 1] = o1 + hb[1];
    }
  }
}

// ---------------------------------------------------------------------------
extern "C" void kernel_launch(void* const* d_in, const int* in_sizes, int n_in,
                              void* d_out, int out_size, void* d_ws, size_t ws_size,
                              hipStream_t stream) {
  const float* tl       = (const float*)d_in[0];
  const float* tr       = (const float*)d_in[1];
  const float* coord_w  = (const float*)d_in[2];
  const float* coord_b  = (const float*)d_in[3];
  const float* pos_emb  = (const float*)d_in[4];
  const float* side_emb = (const float*)d_in[5];
  const float* query_emb= (const float*)d_in[6];
  const float* tln_g    = (const float*)d_in[7];
  const float* tln_b    = (const float*)d_in[8];
  const float* qln_g    = (const float*)d_in[9];
  const float* qln_b    = (const float*)d_in[10];
  const float* ipw      = (const float*)d_in[11];
  const float* ipb      = (const float*)d_in[12];
  const float* opw      = (const float*)d_in[13];
  const float* opb      = (const float*)d_in[14];
  const float* f1w      = (const float*)d_in[15];
  const float* f1b      = (const float*)d_in[16];
  const float* f2w      = (const float*)d_in[17];
  const float* f2b2     = (const float*)d_in[18];
  const float* pag      = (const float*)d_in[19];
  const float* pab      = (const float*)d_in[20];
  const float* pfg      = (const float*)d_in[21];
  const float* pfb      = (const float*)d_in[22];
  const float* hw       = (const float*)d_in[23];
  const float* hb       = (const float*)d_in[24];
  char* ws = (char*)d_ws;

  k_tables<<<21, 128, 0, stream>>>(coord_w, coord_b, pos_emb, side_emb, query_emb,
                                   tln_g, tln_b, qln_g, qln_b, ipw, ipb, ws);
  k_build<<<160, 256, 0, stream>>>(opw, opb, f1w, f2w, ws);
  k_main<<<32768 / GE, 256, 0, stream>>>(tl, tr, f1b, f2b2, pag, pab, pfg, pfb,
                                         hw, hb, ws, (float*)d_out);
}

// Round 5
// 241.332 us; speedup vs baseline: 1.1153x; 1.1153x over previous
//
#include <hip/hip_runtime.h>
#include <hip/hip_bf16.h>

// ---------------------------------------------------------------------------
// TransformerPlanner, round 5 (= R4 with LDS-size fix).
// R4 bug: smem[29728] but X (24x136 bf16 @ offset 25344) extends to 31872 ->
// OOB LDS writes in P4 -> absmax 0.9. Fixed: smem[31872] (as in passing R2).
//  - No runtime-indexed register arrays (scratch-traffic fix vs R2).
//  - B-fragments prefetched across barriers (Bf3 top, Bf5 in P3 tail, Bf6 in
//    P5 tail).
//  - Coords + score tables staged to LDS once per WG (P0).
//  - Single merged k_prep kernel.
// ---------------------------------------------------------------------------

typedef __bf16 bf16x8 __attribute__((ext_vector_type(8)));
typedef float  f32x4  __attribute__((ext_vector_type(4)));
static_assert(sizeof(bf16x8) == 16, "bf16x8 must be 16B");

__device__ __forceinline__ unsigned short f2b(float x) {
  __bf16 h = (__bf16)x;
  return __builtin_bit_cast(unsigned short, h);
}
__device__ __forceinline__ float b2f(unsigned short u) {
  return (float)__builtin_bit_cast(__bf16, u);
}
__device__ __forceinline__ unsigned pack2(float a, float b) {
  return (unsigned)f2b(a) | ((unsigned)f2b(b) << 16);
}
__device__ __forceinline__ float dot4(float4 a, float4 b) {
  return a.x*b.x + a.y*b.y + a.z*b.z + a.w*b.w;
}
__device__ __forceinline__ f32x4 mfma16(bf16x8 a, bf16x8 b, f32x4 c) {
  return __builtin_amdgcn_mfma_f32_16x16x32_bf16(a, b, c, 0, 0, 0);
}

// ---- workspace layout (byte offsets into d_ws) ----
#define WS_OM    0          // ushort[128*192]
#define WS_FC1   49152      // ushort[256*128]
#define WS_FC2   114688     // ushort[128*256]
#define WS_QN    192000     // float[3*128]
#define WS_SB    193536     // float[480]   Sb[w*8+h][20]
#define WS_SU    195456     // float[72]    Su[24],Sw[24],Sc[24]
#define WS_SCAL  195744     // float[3]
#define WS_SUB   195756     // float[20]
#define WS_SWB   195836     // float[20]
#define WS_SBB   195916     // float[20]    (ends 195996; SB..SBB = 615 f32 contiguous)

// ---------------------------------------------------------------------------
__device__ float mean128(float v, volatile float* red) {
  #pragma unroll
  for (int o = 32; o; o >>= 1) v += __shfl_down(v, o, 64);
  __syncthreads();
  if ((threadIdx.x & 63) == 0) red[threadIdx.x >> 6] = v;
  __syncthreads();
  return (red[0] + red[1]) * (1.0f / 128.0f);
}

// One prep kernel. blocks 0..19: token t (stats, Sb, OM token cols).
// block 20: misc (SCAL/Su/Sw/Sc/QN, OM cols 160..191). blocks 21..36: fc1
// repack. blocks 37..52: fc2 repack. 128 threads.
__global__ void k_prep(
    const float* __restrict__ coord_w, const float* __restrict__ coord_b,
    const float* __restrict__ pos_emb, const float* __restrict__ side_emb,
    const float* __restrict__ query_emb,
    const float* __restrict__ tln_g, const float* __restrict__ tln_b,
    const float* __restrict__ qln_g, const float* __restrict__ qln_b,
    const float* __restrict__ ipw, const float* __restrict__ ipb,
    const float* __restrict__ opw, const float* __restrict__ opb,
    const float* __restrict__ f1w, const float* __restrict__ f2w,
    char* __restrict__ ws)
{
  const int t = blockIdx.x, d = threadIdx.x;

  if (t >= 21) {  // fc repack (uniform per block; no barriers below needed)
    const float* srcw = (t < 37) ? f1w : f2w;
    unsigned short* dstw = (unsigned short*)(ws + ((t < 37) ? WS_FC1 : WS_FC2));
    int base = ((t < 37) ? (t - 21) : (t - 37)) * 2048;
    #pragma unroll
    for (int j = 0; j < 4; j++) {
      int i = base + j*512 + d*4;
      float4 v = *(const float4*)(srcw + i);
      uint2 pk; pk.x = pack2(v.x, v.y); pk.y = pack2(v.z, v.w);
      *(uint2*)(dstw + i) = pk;
    }
    return;
  }

  __shared__ float red[2];
  __shared__ float qn[3][128];
  __shared__ float qmat[3][128];
  __shared__ float vecA[128];
  __shared__ float vecB[128];
  __shared__ float vecC[128];
  __shared__ float kuA[128];
  __shared__ float kwA[128];
  __shared__ float kcA[128];
  __shared__ float vuA[128];
  __shared__ float vwA[128];
  __shared__ float vcA[128];

  float u  = coord_w[d*2+0];
  float w2 = coord_w[d*2+1];
  float g  = tln_g[d];
  float mu = mean128(u,  red);
  float mw = mean128(w2, red);
  float uh = u - mu, wh = w2 - mw;

  #pragma unroll
  for (int w = 0; w < 3; w++) {
    float qe = query_emb[w*128 + d];
    float m  = mean128(qe, red);
    float m2 = mean128(qe*qe, red);
    qn[w][d] = (qe - m) * rsqrtf(m2 - m*m + 1e-5f) * qln_g[d] + qln_b[d];
  }
  __syncthreads();
  {
    const float* wqr = ipw + d*128;
    float a0 = 0, a1 = 0, a2 = 0;
    for (int k4 = 0; k4 < 32; k4++) {
      float4 wv4 = *(const float4*)&wqr[k4*4];
      a0 += dot4(wv4, *(const float4*)&qn[0][k4*4]);
      a1 += dot4(wv4, *(const float4*)&qn[1][k4*4]);
      a2 += dot4(wv4, *(const float4*)&qn[2][k4*4]);
    }
    float bq = ipb[d];
    qmat[0][d] = a0 + bq; qmat[1][d] = a1 + bq; qmat[2][d] = a2 + bq;
  }
  __syncthreads();

  unsigned short* OMw = (unsigned short*)(ws + WS_OM);

  if (t < 20) {
    float base = coord_b[d] + pos_emb[(t % 10)*128 + d] + side_emb[(t < 10 ? 0 : 1)*128 + d];
    float mb = mean128(base, red);
    float bh = base - mb;
    float sub = mean128(uh*bh, red);
    float swb = mean128(wh*bh, red);
    float sbb = mean128(bh*bh, red);
    if (d == 0) {
      ((float*)(ws + WS_SUB))[t] = sub;
      ((float*)(ws + WS_SWB))[t] = swb;
      ((float*)(ws + WS_SBB))[t] = sbb;
    }
    vecA[d] = bh * g;
    __syncthreads();
    const float* wkr = ipw + (128 + d)*128;
    const float* wvr = ipw + (256 + d)*128;
    float kb = 0, vb = 0;
    for (int k4 = 0; k4 < 32; k4++) {
      float4 a4 = *(const float4*)&vecA[k4*4];
      kb += dot4(*(const float4*)&wkr[k4*4], a4);
      vb += dot4(*(const float4*)&wvr[k4*4], a4);
    }
    kuA[d] = kb;
    vecB[d] = vb;   // vbA
    __syncthreads();
    if (d < 24) {
      int w = d / 8, h = d % 8;
      float s = 0;
      #pragma unroll
      for (int dl = 0; dl < 16; dl++) s += qmat[w][h*16 + dl] * kuA[h*16 + dl];
      ((float*)(ws + WS_SB))[(w*8 + h)*20 + t] = 0.25f * s;
    }
    // OM token columns: n = d, cols h*20 + t
    const float* orow = opw + d*128;
    #pragma unroll
    for (int h = 0; h < 8; h++) {
      float val = 0;
      #pragma unroll
      for (int dl = 0; dl < 16; dl += 4)
        val += dot4(*(const float4*)&orow[h*16 + dl], *(const float4*)&vecB[h*16 + dl]);
      OMw[d*192 + h*20 + t] = f2b(val);
    }
  } else {
    float suu = mean128(uh*uh, red);
    float sww = mean128(wh*wh, red);
    float suw = mean128(uh*wh, red);
    if (d == 0) {
      float* sc = (float*)(ws + WS_SCAL);
      sc[0] = suu; sc[1] = sww; sc[2] = suw;
    }
    vecA[d] = uh * g; vecB[d] = wh * g; vecC[d] = tln_b[d];
    __syncthreads();
    const float* wkr = ipw + (128 + d)*128;
    const float* wvr = ipw + (256 + d)*128;
    float ku = 0, kw = 0, kc = 0, vu = 0, vw = 0, vc = 0;
    for (int k4 = 0; k4 < 32; k4++) {
      float4 a4 = *(const float4*)&vecA[k4*4];
      float4 b4 = *(const float4*)&vecB[k4*4];
      float4 c4 = *(const float4*)&vecC[k4*4];
      float4 kv = *(const float4*)&wkr[k4*4];
      float4 vv = *(const float4*)&wvr[k4*4];
      ku += dot4(kv, a4); kw += dot4(kv, b4); kc += dot4(kv, c4);
      vu += dot4(vv, a4); vw += dot4(vv, b4); vc += dot4(vv, c4);
    }
    kc += ipb[128 + d]; vc += ipb[256 + d];
    kuA[d] = ku; kwA[d] = kw; kcA[d] = kc;
    vuA[d] = vu; vwA[d] = vw; vcA[d] = vc;
    float* qnw = (float*)(ws + WS_QN);
    qnw[0*128 + d] = qn[0][d]; qnw[1*128 + d] = qn[1][d]; qnw[2*128 + d] = qn[2][d];
    __syncthreads();
    if (d < 24) {
      int w = d / 8, h = d % 8;
      float su = 0, sw = 0, sc2 = 0;
      #pragma unroll
      for (int dl = 0; dl < 16; dl++) {
        float q = qmat[w][h*16 + dl];
        su  += q * kuA[h*16 + dl];
        sw  += q * kwA[h*16 + dl];
        sc2 += q * kcA[h*16 + dl];
      }
      float* o = (float*)(ws + WS_SU);
      o[ 0 + w*8 + h] = 0.25f * su;
      o[24 + w*8 + h] = 0.25f * sw;
      o[48 + w*8 + h] = 0.25f * sc2;
    }
    // OM misc columns 160..191 for row n = d
    const float* orow = opw + d*128;
    float vcdot = 0;
    #pragma unroll
    for (int k4 = 0; k4 < 32; k4++)
      vcdot += dot4(*(const float4*)&orow[k4*4], *(const float4*)&vcA[k4*4]);
    #pragma unroll
    for (int h = 0; h < 8; h++) {
      float a = 0, b = 0;
      #pragma unroll
      for (int dl = 0; dl < 16; dl += 4) {
        float4 o4 = *(const float4*)&orow[h*16 + dl];
        a += dot4(o4, *(const float4*)&vuA[h*16 + dl]);
        b += dot4(o4, *(const float4*)&vwA[h*16 + dl]);
      }
      OMw[d*192 + 160 + h] = f2b(a);
      OMw[d*192 + 168 + h] = f2b(b);
    }
    OMw[d*192 + 176] = f2b(vcdot + opb[d]);
    #pragma unroll
    for (int i = 177; i < 192; i++) OMw[d*192 + i] = 0;
  }
}

// ---------------------------------------------------------------------------
// Main fused kernel: 8 batch elements per WG (M = 24 rows), 256 threads.
// LDS 31872 B; __launch_bounds__(256,4) -> 4 WGs/CU (16 waves).
// LDS map: S1 [0, 12672) ; Z/h1 [12672, 25344) ; X [25344, 31872).
// xs/ysh/rsh/Stab alias the X region (dead after P2; X written in P4).
#define GE 8
#define MR 24

__global__ __launch_bounds__(256, 4) void k_main(
    const float* __restrict__ tl, const float* __restrict__ tr,
    const float* __restrict__ f1b, const float* __restrict__ f2b_,
    const float* __restrict__ pag, const float* __restrict__ pab,
    const float* __restrict__ pfg, const float* __restrict__ pfb,
    const float* __restrict__ hw, const float* __restrict__ hb,
    const char* __restrict__ ws, float* __restrict__ out)
{
  __shared__ __align__(16) char smem[31872];
  float* S1 = (float*)smem;                              // 24 x 132 f32 (attn_out / h2)
  unsigned short* Z  = (unsigned short*)(smem + 12672);  // 24 x 200 bf16 (K=192 used)
  unsigned short* h1 = (unsigned short*)(smem + 12672);  // 24 x 264 bf16 (aliases Z)
  unsigned short* X  = (unsigned short*)(smem + 25344);  // 24 x 136 bf16 (P4..P7)
  float* xs   = (float*)(smem + 25344);                  // 160 (aliases X; dead by P4)
  float* ysh  = (float*)(smem + 25984);                  // 160
  float* rsh  = (float*)(smem + 26624);                  // 160
  float* Stab = (float*)(smem + 27264);                  // 615 f32 tables (dead by P4)

  const unsigned short* OM = (const unsigned short*)(ws + WS_OM);
  const unsigned short* W1 = (const unsigned short*)(ws + WS_FC1);
  const unsigned short* W2 = (const unsigned short*)(ws + WS_FC2);
  const float* QN    = (const float*)(ws + WS_QN);
  const float* SBg   = (const float*)(ws + WS_SB);   // contiguous 615-float table block
  const float* SCALg = (const float*)(ws + WS_SCAL);
  const float* SUBg  = (const float*)(ws + WS_SUB);
  const float* SWBg  = (const float*)(ws + WS_SWB);
  const float* SBBg  = (const float*)(ws + WS_SBB);

  const int tid  = threadIdx.x;
  const int wg   = blockIdx.x;
  const int lane = tid & 63;
  const int wv   = tid >> 6;
  const int quad = lane >> 4;
  const int l15  = lane & 15;

  // ---- prefetch P3 B-fragments (OM) — lands during P0/P2 ----
  bf16x8 Bf3[2][6];
  {
    int n0 = wv*32 + l15;
    #pragma unroll
    for (int nt = 0; nt < 2; nt++)
      #pragma unroll
      for (int kt = 0; kt < 6; kt++)
        Bf3[nt][kt] = *(const bf16x8*)(OM + (n0 + nt*16)*192 + kt*32 + quad*8);
  }

  // ---- P0: coords + rs -> LDS (80 thr); tables -> LDS (154 thr) ----
  if (tid < 80) {
    int half = tid / 40, i4 = tid % 40;
    const float* src = half ? tr : tl;
    float4 v = *(const float4*)(src + wg*160 + i4*4);
    int e = i4 / 5, j = i4 % 5;
    int t0 = half*10 + j*2;
    float suu = SCALg[0], sww = SCALg[1], suw2 = 2.0f*SCALg[2];
    {
      float x = v.x, y = v.y;
      float var = fmaf(suu, x*x, fmaf(sww, y*y, suw2*(x*y)))
                + 2.0f*SUBg[t0]*x + 2.0f*SWBg[t0]*y + SBBg[t0];
      float rv = rsqrtf(var + 1e-5f);
      xs[e*20 + t0] = x*rv; ysh[e*20 + t0] = y*rv; rsh[e*20 + t0] = rv;
    }
    {
      float x = v.z, y = v.w;
      int t1 = t0 + 1;
      float var = fmaf(suu, x*x, fmaf(sww, y*y, suw2*(x*y)))
                + 2.0f*SUBg[t1]*x + 2.0f*SWBg[t1]*y + SBBg[t1];
      float rv = rsqrtf(var + 1e-5f);
      xs[e*20 + t1] = x*rv; ysh[e*20 + t1] = y*rv; rsh[e*20 + t1] = rv;
    }
  } else {
    int i = tid - 80;           // 0..175
    if (i < 153) {
      *(float4*)&Stab[i*4] = *(const float4*)(SBg + i*4);
    } else if (i == 153) {
      Stab[612] = SBg[612]; Stab[613] = SBg[613]; Stab[614] = SBg[614];
    }
  }
  if (tid < MR) {               // constant tail of Z rows
    *(uint4*)(Z + tid*200 + 176) = uint4{0x3F80u, 0u, 0u, 0u};
    *(uint4*)(Z + tid*200 + 184) = uint4{0u, 0u, 0u, 0u};
  }
  __syncthreads();

  // ---- P2: scores + softmax + P,Q -> Z (256 thr: e,h,q) ----
  {
    int e = tid >> 5, h = (tid >> 2) & 7, q = tid & 3;
    float xa[5], ya[5], ra[5];
    #pragma unroll
    for (int j = 0; j < 5; j++) {
      int idx = e*20 + q*5 + j;
      xa[j] = xs[idx]; ya[j] = ysh[idx]; ra[j] = rsh[idx];
    }
    unsigned short* Zr0 = Z + e*3*200;
    #pragma unroll
    for (int w = 0; w < 3; w++) {
      float suv = Stab[480 + w*8 + h];
      float swv = Stab[504 + w*8 + h];
      float scv = Stab[528 + w*8 + h];
      const float* sb = &Stab[(w*8 + h)*20 + q*5];
      float s[5];
      float m = -1e30f;
      #pragma unroll
      for (int j = 0; j < 5; j++) {
        s[j] = fmaf(xa[j], suv, fmaf(ya[j], swv, fmaf(ra[j], sb[j], scv)));
        m = fmaxf(m, s[j]);
      }
      m = fmaxf(m, __shfl_xor(m, 1));
      m = fmaxf(m, __shfl_xor(m, 2));
      float sum = 0, P = 0, Q = 0;
      #pragma unroll
      for (int j = 0; j < 5; j++) {
        float p = __expf(s[j] - m);
        s[j] = p; sum += p;
        P = fmaf(p, xa[j], P); Q = fmaf(p, ya[j], Q);
      }
      sum += __shfl_xor(sum, 1); sum += __shfl_xor(sum, 2);
      P   += __shfl_xor(P, 1);   P   += __shfl_xor(P, 2);
      Q   += __shfl_xor(Q, 1);   Q   += __shfl_xor(Q, 2);
      float inv = 1.0f / sum;
      unsigned short* Zr = Zr0 + w*200;
      #pragma unroll
      for (int j = 0; j < 5; j++) Zr[h*20 + q*5 + j] = f2b(s[j]*ra[j]*inv);
      if (q == 0) { Zr[160 + h] = f2b(P*inv); Zr[168 + h] = f2b(Q*inv); }
    }
  }
  __syncthreads();

  // ---- P3: GEMM1  attn_out(24x128) = Z(24x192) @ OM^T ----
  bf16x8 Bf5[4][4];
  {
    int r0c = l15;
    int r1c = min(16 + l15, 23);
    f32x4 acc[2][2];
    #pragma unroll
    for (int mt = 0; mt < 2; mt++)
      #pragma unroll
      for (int nt = 0; nt < 2; nt++) acc[mt][nt] = (f32x4){0.f,0.f,0.f,0.f};
    #pragma unroll
    for (int kt = 0; kt < 6; kt++) {
      int k = kt*32 + quad*8;
      bf16x8 Af0 = *(const bf16x8*)(Z + r0c*200 + k);
      bf16x8 Af1 = *(const bf16x8*)(Z + r1c*200 + k);
      acc[0][0] = mfma16(Af0, Bf3[0][kt], acc[0][0]);
      acc[0][1] = mfma16(Af0, Bf3[1][kt], acc[0][1]);
      acc[1][0] = mfma16(Af1, Bf3[0][kt], acc[1][0]);
      acc[1][1] = mfma16(Af1, Bf3[1][kt], acc[1][1]);
    }
    #pragma unroll
    for (int mt = 0; mt < 2; mt++) {
      if (mt == 1 && quad >= 2) break;     // rows >= 24 are garbage
      #pragma unroll
      for (int nt = 0; nt < 2; nt++) {
        int col = wv*32 + nt*16 + l15;
        int r0  = mt*16 + quad*4;
        #pragma unroll
        for (int j = 0; j < 4; j++) S1[(r0 + j)*132 + col] = acc[mt][nt][j];
      }
    }
    // prefetch P5 B-fragments (W1) — lands during P4
    #pragma unroll
    for (int nt = 0; nt < 4; nt++)
      #pragma unroll
      for (int kt = 0; kt < 4; kt++)
        Bf5[nt][kt] = *(const bf16x8*)(W1 + (wv*64 + nt*16 + l15)*128 + kt*32 + quad*8);
  }
  __syncthreads();

  // ---- P4: x = LN(queries_n + attn_out) -> X bf16  (192 thr, 8/row) ----
  if (tid < 192) {
    int r = tid >> 3, p = tid & 7, w = r % 3;
    float4 v0 = *(float4*)&S1[r*132 + p*16 + 0];
    float4 v1 = *(float4*)&S1[r*132 + p*16 + 4];
    float4 v2 = *(float4*)&S1[r*132 + p*16 + 8];
    float4 v3 = *(float4*)&S1[r*132 + p*16 + 12];
    const float* qrow = QN + w*128 + p*16;
    float4 q0 = *(const float4*)(qrow + 0);
    float4 q1 = *(const float4*)(qrow + 4);
    float4 q2 = *(const float4*)(qrow + 8);
    float4 q3 = *(const float4*)(qrow + 12);
    v0.x+=q0.x; v0.y+=q0.y; v0.z+=q0.z; v0.w+=q0.w;
    v1.x+=q1.x; v1.y+=q1.y; v1.z+=q1.z; v1.w+=q1.w;
    v2.x+=q2.x; v2.y+=q2.y; v2.z+=q2.z; v2.w+=q2.w;
    v3.x+=q3.x; v3.y+=q3.y; v3.z+=q3.z; v3.w+=q3.w;
    float s1 = (v0.x+v0.y+v0.z+v0.w) + (v1.x+v1.y+v1.z+v1.w)
             + (v2.x+v2.y+v2.z+v2.w) + (v3.x+v3.y+v3.z+v3.w);
    float s2 = dot4(v0,v0) + dot4(v1,v1) + dot4(v2,v2) + dot4(v3,v3);
    #pragma unroll
    for (int o = 1; o < 8; o <<= 1) { s1 += __shfl_xor(s1, o); s2 += __shfl_xor(s2, o); }
    float m  = s1 * (1.0f/128.0f);
    float sc = rsqrtf(s2 * (1.0f/128.0f) - m*m + 1e-5f);
    float4 g0 = *(const float4*)(pag + p*16 + 0);
    float4 g1 = *(const float4*)(pag + p*16 + 4);
    float4 g2 = *(const float4*)(pag + p*16 + 8);
    float4 g3 = *(const float4*)(pag + p*16 + 12);
    float4 b0 = *(const float4*)(pab + p*16 + 0);
    float4 b1 = *(const float4*)(pab + p*16 + 4);
    float4 b2 = *(const float4*)(pab + p*16 + 8);
    float4 b3 = *(const float4*)(pab + p*16 + 12);
    uint4 pkA, pkB;
    pkA.x = pack2((v0.x-m)*sc*g0.x+b0.x, (v0.y-m)*sc*g0.y+b0.y);
    pkA.y = pack2((v0.z-m)*sc*g0.z+b0.z, (v0.w-m)*sc*g0.w+b0.w);
    pkA.z = pack2((v1.x-m)*sc*g1.x+b1.x, (v1.y-m)*sc*g1.y+b1.y);
    pkA.w = pack2((v1.z-m)*sc*g1.z+b1.z, (v1.w-m)*sc*g1.w+b1.w);
    pkB.x = pack2((v2.x-m)*sc*g2.x+b2.x, (v2.y-m)*sc*g2.y+b2.y);
    pkB.y = pack2((v2.z-m)*sc*g2.z+b2.z, (v2.w-m)*sc*g2.w+b2.w);
    pkB.z = pack2((v3.x-m)*sc*g3.x+b3.x, (v3.y-m)*sc*g3.y+b3.y);
    pkB.w = pack2((v3.z-m)*sc*g3.z+b3.z, (v3.w-m)*sc*g3.w+b3.w);
    *(uint4*)&X[r*136 + p*16]     = pkA;
    *(uint4*)&X[r*136 + p*16 + 8] = pkB;
  }
  __syncthreads();

  // ---- P5: fc1 + relu -> h1 bf16 (24x256) ----
  bf16x8 Bf6[2][8];
  {
    int r0c = l15;
    int r1c = min(16 + l15, 23);
    f32x4 acc[2][4];
    #pragma unroll
    for (int mt = 0; mt < 2; mt++)
      #pragma unroll
      for (int nt = 0; nt < 4; nt++) acc[mt][nt] = (f32x4){0.f,0.f,0.f,0.f};
    #pragma unroll
    for (int kt = 0; kt < 4; kt++) {
      int k = kt*32 + quad*8;
      bf16x8 Af0 = *(const bf16x8*)(X + r0c*136 + k);
      bf16x8 Af1 = *(const bf16x8*)(X + r1c*136 + k);
      #pragma unroll
      for (int nt = 0; nt < 4; nt++) {
        acc[0][nt] = mfma16(Af0, Bf5[nt][kt], acc[0][nt]);
        acc[1][nt] = mfma16(Af1, Bf5[nt][kt], acc[1][nt]);
      }
    }
    #pragma unroll
    for (int nt = 0; nt < 4; nt++) {
      int col = wv*64 + nt*16 + l15;
      float bb = f1b[col];
      #pragma unroll
      for (int mt = 0; mt < 2; mt++) {
        if (mt == 1 && quad >= 2) break;
        int r0 = mt*16 + quad*4;
        #pragma unroll
        for (int j = 0; j < 4; j++)
          h1[(r0 + j)*264 + col] = f2b(fmaxf(acc[mt][nt][j] + bb, 0.0f));
      }
    }
    // prefetch P6 B-fragments (W2) — lands across the barrier
    #pragma unroll
    for (int nt = 0; nt < 2; nt++)
      #pragma unroll
      for (int kt = 0; kt < 8; kt++)
        Bf6[nt][kt] = *(const bf16x8*)(W2 + (wv*32 + nt*16 + l15)*256 + kt*32 + quad*8);
  }
  __syncthreads();

  // ---- P6: h2 = h1 @ fc2^T + b -> S1 f32 ----
  {
    int r0c = l15;
    int r1c = min(16 + l15, 23);
    f32x4 acc[2][2];
    #pragma unroll
    for (int mt = 0; mt < 2; mt++)
      #pragma unroll
      for (int nt = 0; nt < 2; nt++) acc[mt][nt] = (f32x4){0.f,0.f,0.f,0.f};
    #pragma unroll
    for (int kt = 0; kt < 8; kt++) {
      int k = kt*32 + quad*8;
      bf16x8 Af0 = *(const bf16x8*)(h1 + r0c*264 + k);
      bf16x8 Af1 = *(const bf16x8*)(h1 + r1c*264 + k);
      acc[0][0] = mfma16(Af0, Bf6[0][kt], acc[0][0]);
      acc[0][1] = mfma16(Af0, Bf6[1][kt], acc[0][1]);
      acc[1][0] = mfma16(Af1, Bf6[0][kt], acc[1][0]);
      acc[1][1] = mfma16(Af1, Bf6[1][kt], acc[1][1]);
    }
    __syncthreads();   // h1 fully consumed before S1 region reuse below
    #pragma unroll
    for (int mt = 0; mt < 2; mt++) {
      if (mt == 1 && quad >= 2) break;
      #pragma unroll
      for (int nt = 0; nt < 2; nt++) {
        int col = wv*32 + nt*16 + l15;
        float bb = f2b_[col];
        int r0 = mt*16 + quad*4;
        #pragma unroll
        for (int j = 0; j < 4; j++) S1[(r0 + j)*132 + col] = acc[mt][nt][j] + bb;
      }
    }
  }
  __syncthreads();

  // ---- P7: x2 = LN(x + h2); out = x2 @ head^T + hb  (192 thr, 8/row) ----
  if (tid < 192) {
    int r = tid >> 3, p = tid & 7;
    int e = r / 3, w = r % 3;
    float4 v0 = *(float4*)&S1[r*132 + p*16 + 0];
    float4 v1 = *(float4*)&S1[r*132 + p*16 + 4];
    float4 v2 = *(float4*)&S1[r*132 + p*16 + 8];
    float4 v3 = *(float4*)&S1[r*132 + p*16 + 12];
    uint4 u0 = *(const uint4*)&X[r*136 + p*16];
    uint4 u1 = *(const uint4*)&X[r*136 + p*16 + 8];
    v0.x += b2f(u0.x&0xffff); v0.y += b2f(u0.x>>16);
    v0.z += b2f(u0.y&0xffff); v0.w += b2f(u0.y>>16);
    v1.x += b2f(u0.z&0xffff); v1.y += b2f(u0.z>>16);
    v1.z += b2f(u0.w&0xffff); v1.w += b2f(u0.w>>16);
    v2.x += b2f(u1.x&0xffff); v2.y += b2f(u1.x>>16);
    v2.z += b2f(u1.y&0xffff); v2.w += b2f(u1.y>>16);
    v3.x += b2f(u1.z&0xffff); v3.y += b2f(u1.z>>16);
    v3.z += b2f(u1.w&0xffff); v3.w += b2f(u1.w>>16);
    float s1 = (v0.x+v0.y+v0.z+v0.w) + (v1.x+v1.y+v1.z+v1.w)
             + (v2.x+v2.y+v2.z+v2.w) + (v3.x+v3.y+v3.z+v3.w);
    float s2 = dot4(v0,v0) + dot4(v1,v1) + dot4(v2,v2) + dot4(v3,v3);
    #pragma unroll
    for (int o = 1; o < 8; o <<= 1) { s1 += __shfl_xor(s1, o); s2 += __shfl_xor(s2, o); }
    float m  = s1 * (1.0f/128.0f);
    float sc = rsqrtf(s2 * (1.0f/128.0f) - m*m + 1e-5f);
    float o0 = 0, o1 = 0;
    #pragma unroll
    for (int i = 0; i < 4; i++) {
      float4 vv = (i==0) ? v0 : (i==1) ? v1 : (i==2) ? v2 : v3;
      float4 g4 = *(const float4*)(pfg + p*16 + i*4);
      float4 b4 = *(const float4*)(pfb + p*16 + i*4);
      float4 h0 = *(const float4*)(hw + p*16 + i*4);
      float4 h8 = *(const float4*)(hw + 128 + p*16 + i*4);
      float x0 = (vv.x - m)*sc*g4.x + b4.x;
      float x1 = (vv.y - m)*sc*g4.y + b4.y;
      float x2 = (vv.z - m)*sc*g4.z + b4.z;
      float x3 = (vv.w - m)*sc*g4.w + b4.w;
      o0 = fmaf(x0,h0.x, fmaf(x1,h0.y, fmaf(x2,h0.z, fmaf(x3,h0.w, o0))));
      o1 = fmaf(x0,h8.x, fmaf(x1,h8.y, fmaf(x2,h8.z, fmaf(x3,h8.w, o1))));
    }
    #pragma unroll
    for (int o = 1; o < 8; o <<= 1) { o0 += __shfl_xor(o0, o); o1 += __shfl_xor(o1, o); }
    if (p == 0) {
      int gi = ((wg*GE + e)*3 + w)*2;
      out[gi]     = o0 + hb[0];
      out[gi + 1] = o1 + hb[1];
    }
  }
}

// ---------------------------------------------------------------------------
extern "C" void kernel_launch(void* const* d_in, const int* in_sizes, int n_in,
                              void* d_out, int out_size, void* d_ws, size_t ws_size,
                              hipStream_t stream) {
  const float* tl       = (const float*)d_in[0];
  const float* tr       = (const float*)d_in[1];
  const float* coord_w  = (const float*)d_in[2];
  const float* coord_b  = (const float*)d_in[3];
  const float* pos_emb  = (const float*)d_in[4];
  const float* side_emb = (const float*)d_in[5];
  const float* query_emb= (const float*)d_in[6];
  const float* tln_g    = (const float*)d_in[7];
  const float* tln_b    = (const float*)d_in[8];
  const float* qln_g    = (const float*)d_in[9];
  const float* qln_b    = (const float*)d_in[10];
  const float* ipw      = (const float*)d_in[11];
  const float* ipb      = (const float*)d_in[12];
  const float* opw      = (const float*)d_in[13];
  const float* opb      = (const float*)d_in[14];
  const float* f1w      = (const float*)d_in[15];
  const float* f1b      = (const float*)d_in[16];
  const float* f2w      = (const float*)d_in[17];
  const float* f2b2     = (const float*)d_in[18];
  const float* pag      = (const float*)d_in[19];
  const float* pab      = (const float*)d_in[20];
  const float* pfg      = (const float*)d_in[21];
  const float* pfb      = (const float*)d_in[22];
  const float* hw       = (const float*)d_in[23];
  const float* hb       = (const float*)d_in[24];
  char* ws = (char*)d_ws;

  k_prep<<<53, 128, 0, stream>>>(coord_w, coord_b, pos_emb, side_emb, query_emb,
                                 tln_g, tln_b, qln_g, qln_b, ipw, ipb,
                                 opw, opb, f1w, f2w, ws);
  k_main<<<32768 / GE, 256, 0, stream>>>(tl, tr, f1b, f2b2, pag, pab, pfg, pfb,
                                         hw, hb, ws, (float*)d_out);
}

// Round 6
// 229.819 us; speedup vs baseline: 1.1712x; 1.0501x over previous
//
#include <hip/hip_runtime.h>
#include <hip/hip_bf16.h>

// ---------------------------------------------------------------------------
// TransformerPlanner, round 6.
// R5 post-mortem: cross-barrier B-fragment prefetch (176 VGPRs live across
// barriers) spilled to scratch -> 95 MB HBM write traffic. R6: B-fragments
// loaded batched WITHIN each GEMM phase scope (R1's proven spill-free
// pattern, VGPR 88 / WRITE 768 KB there). Also removed the unnecessary
// mid-P6 barrier (S1 and h1 LDS regions are disjoint).
// ---------------------------------------------------------------------------

typedef __bf16 bf16x8 __attribute__((ext_vector_type(8)));
typedef float  f32x4  __attribute__((ext_vector_type(4)));
static_assert(sizeof(bf16x8) == 16, "bf16x8 must be 16B");

__device__ __forceinline__ unsigned short f2b(float x) {
  __bf16 h = (__bf16)x;
  return __builtin_bit_cast(unsigned short, h);
}
__device__ __forceinline__ float b2f(unsigned short u) {
  return (float)__builtin_bit_cast(__bf16, u);
}
__device__ __forceinline__ unsigned pack2(float a, float b) {
  return (unsigned)f2b(a) | ((unsigned)f2b(b) << 16);
}
__device__ __forceinline__ float dot4(float4 a, float4 b) {
  return a.x*b.x + a.y*b.y + a.z*b.z + a.w*b.w;
}
__device__ __forceinline__ f32x4 mfma16(bf16x8 a, bf16x8 b, f32x4 c) {
  return __builtin_amdgcn_mfma_f32_16x16x32_bf16(a, b, c, 0, 0, 0);
}

// ---- workspace layout (byte offsets into d_ws) ----
#define WS_OM    0          // ushort[128*192]
#define WS_FC1   49152      // ushort[256*128]
#define WS_FC2   114688     // ushort[128*256]
#define WS_QN    192000     // float[3*128]
#define WS_SB    193536     // float[480]   Sb[w*8+h][20]
#define WS_SU    195456     // float[72]    Su[24],Sw[24],Sc[24]
#define WS_SCAL  195744     // float[3]
#define WS_SUB   195756     // float[20]
#define WS_SWB   195836     // float[20]
#define WS_SBB   195916     // float[20]    (ends 195996; SB..SBB = 615 f32 contiguous)

// ---------------------------------------------------------------------------
__device__ float mean128(float v, volatile float* red) {
  #pragma unroll
  for (int o = 32; o; o >>= 1) v += __shfl_down(v, o, 64);
  __syncthreads();
  if ((threadIdx.x & 63) == 0) red[threadIdx.x >> 6] = v;
  __syncthreads();
  return (red[0] + red[1]) * (1.0f / 128.0f);
}

// One prep kernel. blocks 0..19: token t (stats, Sb, OM token cols).
// block 20: misc (SCAL/Su/Sw/Sc/QN, OM cols 160..191). blocks 21..36: fc1
// repack. blocks 37..52: fc2 repack. 128 threads.
__global__ void k_prep(
    const float* __restrict__ coord_w, const float* __restrict__ coord_b,
    const float* __restrict__ pos_emb, const float* __restrict__ side_emb,
    const float* __restrict__ query_emb,
    const float* __restrict__ tln_g, const float* __restrict__ tln_b,
    const float* __restrict__ qln_g, const float* __restrict__ qln_b,
    const float* __restrict__ ipw, const float* __restrict__ ipb,
    const float* __restrict__ opw, const float* __restrict__ opb,
    const float* __restrict__ f1w, const float* __restrict__ f2w,
    char* __restrict__ ws)
{
  const int t = blockIdx.x, d = threadIdx.x;

  if (t >= 21) {  // fc repack (uniform per block; no barriers below needed)
    const float* srcw = (t < 37) ? f1w : f2w;
    unsigned short* dstw = (unsigned short*)(ws + ((t < 37) ? WS_FC1 : WS_FC2));
    int base = ((t < 37) ? (t - 21) : (t - 37)) * 2048;
    #pragma unroll
    for (int j = 0; j < 4; j++) {
      int i = base + j*512 + d*4;
      float4 v = *(const float4*)(srcw + i);
      uint2 pk; pk.x = pack2(v.x, v.y); pk.y = pack2(v.z, v.w);
      *(uint2*)(dstw + i) = pk;
    }
    return;
  }

  __shared__ float red[2];
  __shared__ float qn[3][128];
  __shared__ float qmat[3][128];
  __shared__ float vecA[128];
  __shared__ float vecB[128];
  __shared__ float vecC[128];
  __shared__ float kuA[128];
  __shared__ float kwA[128];
  __shared__ float kcA[128];
  __shared__ float vuA[128];
  __shared__ float vwA[128];
  __shared__ float vcA[128];

  float u  = coord_w[d*2+0];
  float w2 = coord_w[d*2+1];
  float g  = tln_g[d];
  float mu = mean128(u,  red);
  float mw = mean128(w2, red);
  float uh = u - mu, wh = w2 - mw;

  #pragma unroll
  for (int w = 0; w < 3; w++) {
    float qe = query_emb[w*128 + d];
    float m  = mean128(qe, red);
    float m2 = mean128(qe*qe, red);
    qn[w][d] = (qe - m) * rsqrtf(m2 - m*m + 1e-5f) * qln_g[d] + qln_b[d];
  }
  __syncthreads();
  {
    const float* wqr = ipw + d*128;
    float a0 = 0, a1 = 0, a2 = 0;
    for (int k4 = 0; k4 < 32; k4++) {
      float4 wv4 = *(const float4*)&wqr[k4*4];
      a0 += dot4(wv4, *(const float4*)&qn[0][k4*4]);
      a1 += dot4(wv4, *(const float4*)&qn[1][k4*4]);
      a2 += dot4(wv4, *(const float4*)&qn[2][k4*4]);
    }
    float bq = ipb[d];
    qmat[0][d] = a0 + bq; qmat[1][d] = a1 + bq; qmat[2][d] = a2 + bq;
  }
  __syncthreads();

  unsigned short* OMw = (unsigned short*)(ws + WS_OM);

  if (t < 20) {
    float base = coord_b[d] + pos_emb[(t % 10)*128 + d] + side_emb[(t < 10 ? 0 : 1)*128 + d];
    float mb = mean128(base, red);
    float bh = base - mb;
    float sub = mean128(uh*bh, red);
    float swb = mean128(wh*bh, red);
    float sbb = mean128(bh*bh, red);
    if (d == 0) {
      ((float*)(ws + WS_SUB))[t] = sub;
      ((float*)(ws + WS_SWB))[t] = swb;
      ((float*)(ws + WS_SBB))[t] = sbb;
    }
    vecA[d] = bh * g;
    __syncthreads();
    const float* wkr = ipw + (128 + d)*128;
    const float* wvr = ipw + (256 + d)*128;
    float kb = 0, vb = 0;
    for (int k4 = 0; k4 < 32; k4++) {
      float4 a4 = *(const float4*)&vecA[k4*4];
      kb += dot4(*(const float4*)&wkr[k4*4], a4);
      vb += dot4(*(const float4*)&wvr[k4*4], a4);
    }
    kuA[d] = kb;
    vecB[d] = vb;   // vbA
    __syncthreads();
    if (d < 24) {
      int w = d / 8, h = d % 8;
      float s = 0;
      #pragma unroll
      for (int dl = 0; dl < 16; dl++) s += qmat[w][h*16 + dl] * kuA[h*16 + dl];
      ((float*)(ws + WS_SB))[(w*8 + h)*20 + t] = 0.25f * s;
    }
    // OM token columns: n = d, cols h*20 + t
    const float* orow = opw + d*128;
    #pragma unroll
    for (int h = 0; h < 8; h++) {
      float val = 0;
      #pragma unroll
      for (int dl = 0; dl < 16; dl += 4)
        val += dot4(*(const float4*)&orow[h*16 + dl], *(const float4*)&vecB[h*16 + dl]);
      OMw[d*192 + h*20 + t] = f2b(val);
    }
  } else {
    float suu = mean128(uh*uh, red);
    float sww = mean128(wh*wh, red);
    float suw = mean128(uh*wh, red);
    if (d == 0) {
      float* sc = (float*)(ws + WS_SCAL);
      sc[0] = suu; sc[1] = sww; sc[2] = suw;
    }
    vecA[d] = uh * g; vecB[d] = wh * g; vecC[d] = tln_b[d];
    __syncthreads();
    const float* wkr = ipw + (128 + d)*128;
    const float* wvr = ipw + (256 + d)*128;
    float ku = 0, kw = 0, kc = 0, vu = 0, vw = 0, vc = 0;
    for (int k4 = 0; k4 < 32; k4++) {
      float4 a4 = *(const float4*)&vecA[k4*4];
      float4 b4 = *(const float4*)&vecB[k4*4];
      float4 c4 = *(const float4*)&vecC[k4*4];
      float4 kv = *(const float4*)&wkr[k4*4];
      float4 vv = *(const float4*)&wvr[k4*4];
      ku += dot4(kv, a4); kw += dot4(kv, b4); kc += dot4(kv, c4);
      vu += dot4(vv, a4); vw += dot4(vv, b4); vc += dot4(vv, c4);
    }
    kc += ipb[128 + d]; vc += ipb[256 + d];
    kuA[d] = ku; kwA[d] = kw; kcA[d] = kc;
    vuA[d] = vu; vwA[d] = vw; vcA[d] = vc;
    float* qnw = (float*)(ws + WS_QN);
    qnw[0*128 + d] = qn[0][d]; qnw[1*128 + d] = qn[1][d]; qnw[2*128 + d] = qn[2][d];
    __syncthreads();
    if (d < 24) {
      int w = d / 8, h = d % 8;
      float su = 0, sw = 0, sc2 = 0;
      #pragma unroll
      for (int dl = 0; dl < 16; dl++) {
        float q = qmat[w][h*16 + dl];
        su  += q * kuA[h*16 + dl];
        sw  += q * kwA[h*16 + dl];
        sc2 += q * kcA[h*16 + dl];
      }
      float* o = (float*)(ws + WS_SU);
      o[ 0 + w*8 + h] = 0.25f * su;
      o[24 + w*8 + h] = 0.25f * sw;
      o[48 + w*8 + h] = 0.25f * sc2;
    }
    // OM misc columns 160..191 for row n = d
    const float* orow = opw + d*128;
    float vcdot = 0;
    #pragma unroll
    for (int k4 = 0; k4 < 32; k4++)
      vcdot += dot4(*(const float4*)&orow[k4*4], *(const float4*)&vcA[k4*4]);
    #pragma unroll
    for (int h = 0; h < 8; h++) {
      float a = 0, b = 0;
      #pragma unroll
      for (int dl = 0; dl < 16; dl += 4) {
        float4 o4 = *(const float4*)&orow[h*16 + dl];
        a += dot4(o4, *(const float4*)&vuA[h*16 + dl]);
        b += dot4(o4, *(const float4*)&vwA[h*16 + dl]);
      }
      OMw[d*192 + 160 + h] = f2b(a);
      OMw[d*192 + 168 + h] = f2b(b);
    }
    OMw[d*192 + 176] = f2b(vcdot + opb[d]);
    #pragma unroll
    for (int i = 177; i < 192; i++) OMw[d*192 + i] = 0;
  }
}

// ---------------------------------------------------------------------------
// Main fused kernel: 8 batch elements per WG (M = 24 rows), 256 threads.
// LDS 31872 B; __launch_bounds__(256,4) -> 4 WGs/CU (16 waves).
// LDS map: S1 [0, 12672) ; Z/h1 [12672, 25344) ; X [25344, 31872).
// xs/ysh/rsh/Stab alias the X region (dead after P2; X written in P4).
#define GE 8
#define MR 24

__global__ __launch_bounds__(256, 4) void k_main(
    const float* __restrict__ tl, const float* __restrict__ tr,
    const float* __restrict__ f1b, const float* __restrict__ f2b_,
    const float* __restrict__ pag, const float* __restrict__ pab,
    const float* __restrict__ pfg, const float* __restrict__ pfb,
    const float* __restrict__ hw, const float* __restrict__ hb,
    const char* __restrict__ ws, float* __restrict__ out)
{
  __shared__ __align__(16) char smem[31872];
  float* S1 = (float*)smem;                              // 24 x 132 f32 (attn_out / h2)
  unsigned short* Z  = (unsigned short*)(smem + 12672);  // 24 x 200 bf16 (K=192 used)
  unsigned short* h1 = (unsigned short*)(smem + 12672);  // 24 x 264 bf16 (aliases Z)
  unsigned short* X  = (unsigned short*)(smem + 25344);  // 24 x 136 bf16 (P4..P7)
  float* xs   = (float*)(smem + 25344);                  // 160 (aliases X; dead by P4)
  float* ysh  = (float*)(smem + 25984);                  // 160
  float* rsh  = (float*)(smem + 26624);                  // 160
  float* Stab = (float*)(smem + 27264);                  // 615 f32 tables (dead by P4)

  const unsigned short* OM = (const unsigned short*)(ws + WS_OM);
  const unsigned short* W1 = (const unsigned short*)(ws + WS_FC1);
  const unsigned short* W2 = (const unsigned short*)(ws + WS_FC2);
  const float* QN    = (const float*)(ws + WS_QN);
  const float* SBg   = (const float*)(ws + WS_SB);   // contiguous 615-float table block
  const float* SCALg = (const float*)(ws + WS_SCAL);
  const float* SUBg  = (const float*)(ws + WS_SUB);
  const float* SWBg  = (const float*)(ws + WS_SWB);
  const float* SBBg  = (const float*)(ws + WS_SBB);

  const int tid  = threadIdx.x;
  const int wg   = blockIdx.x;
  const int lane = tid & 63;
  const int wv   = tid >> 6;
  const int quad = lane >> 4;
  const int l15  = lane & 15;

  // ---- P0: coords + rs -> LDS (80 thr); tables -> LDS (154 thr) ----
  if (tid < 80) {
    int half = tid / 40, i4 = tid % 40;
    const float* src = half ? tr : tl;
    float4 v = *(const float4*)(src + wg*160 + i4*4);
    int e = i4 / 5, j = i4 % 5;
    int t0 = half*10 + j*2;
    float suu = SCALg[0], sww = SCALg[1], suw2 = 2.0f*SCALg[2];
    {
      float x = v.x, y = v.y;
      float var = fmaf(suu, x*x, fmaf(sww, y*y, suw2*(x*y)))
                + 2.0f*SUBg[t0]*x + 2.0f*SWBg[t0]*y + SBBg[t0];
      float rv = rsqrtf(var + 1e-5f);
      xs[e*20 + t0] = x*rv; ysh[e*20 + t0] = y*rv; rsh[e*20 + t0] = rv;
    }
    {
      float x = v.z, y = v.w;
      int t1 = t0 + 1;
      float var = fmaf(suu, x*x, fmaf(sww, y*y, suw2*(x*y)))
                + 2.0f*SUBg[t1]*x + 2.0f*SWBg[t1]*y + SBBg[t1];
      float rv = rsqrtf(var + 1e-5f);
      xs[e*20 + t1] = x*rv; ysh[e*20 + t1] = y*rv; rsh[e*20 + t1] = rv;
    }
  } else {
    int i = tid - 80;           // 0..175
    if (i < 153) {
      *(float4*)&Stab[i*4] = *(const float4*)(SBg + i*4);
    } else if (i == 153) {
      Stab[612] = SBg[612]; Stab[613] = SBg[613]; Stab[614] = SBg[614];
    }
  }
  if (tid < MR) {               // constant tail of Z rows
    *(uint4*)(Z + tid*200 + 176) = uint4{0x3F80u, 0u, 0u, 0u};
    *(uint4*)(Z + tid*200 + 184) = uint4{0u, 0u, 0u, 0u};
  }
  __syncthreads();

  // ---- P2: scores + softmax + P,Q -> Z (256 thr: e,h,q) ----
  {
    int e = tid >> 5, h = (tid >> 2) & 7, q = tid & 3;
    float xa[5], ya[5], ra[5];
    #pragma unroll
    for (int j = 0; j < 5; j++) {
      int idx = e*20 + q*5 + j;
      xa[j] = xs[idx]; ya[j] = ysh[idx]; ra[j] = rsh[idx];
    }
    unsigned short* Zr0 = Z + e*3*200;
    #pragma unroll
    for (int w = 0; w < 3; w++) {
      float suv = Stab[480 + w*8 + h];
      float swv = Stab[504 + w*8 + h];
      float scv = Stab[528 + w*8 + h];
      const float* sb = &Stab[(w*8 + h)*20 + q*5];
      float s[5];
      float m = -1e30f;
      #pragma unroll
      for (int j = 0; j < 5; j++) {
        s[j] = fmaf(xa[j], suv, fmaf(ya[j], swv, fmaf(ra[j], sb[j], scv)));
        m = fmaxf(m, s[j]);
      }
      m = fmaxf(m, __shfl_xor(m, 1));
      m = fmaxf(m, __shfl_xor(m, 2));
      float sum = 0, P = 0, Q = 0;
      #pragma unroll
      for (int j = 0; j < 5; j++) {
        float p = __expf(s[j] - m);
        s[j] = p; sum += p;
        P = fmaf(p, xa[j], P); Q = fmaf(p, ya[j], Q);
      }
      sum += __shfl_xor(sum, 1); sum += __shfl_xor(sum, 2);
      P   += __shfl_xor(P, 1);   P   += __shfl_xor(P, 2);
      Q   += __shfl_xor(Q, 1);   Q   += __shfl_xor(Q, 2);
      float inv = 1.0f / sum;
      unsigned short* Zr = Zr0 + w*200;
      #pragma unroll
      for (int j = 0; j < 5; j++) Zr[h*20 + q*5 + j] = f2b(s[j]*ra[j]*inv);
      if (q == 0) { Zr[160 + h] = f2b(P*inv); Zr[168 + h] = f2b(Q*inv); }
    }
  }
  __syncthreads();

  // ---- P3: GEMM1  attn_out(24x128) = Z(24x192) @ OM^T ----
  // B-fragments loaded batched INSIDE phase scope (no cross-barrier lifetime).
  {
    bf16x8 Bf[2][6];
    #pragma unroll
    for (int nt = 0; nt < 2; nt++)
      #pragma unroll
      for (int kt = 0; kt < 6; kt++)
        Bf[nt][kt] = *(const bf16x8*)(OM + (wv*32 + nt*16 + l15)*192 + kt*32 + quad*8);
    int r0c = l15;
    int r1c = min(16 + l15, 23);
    f32x4 acc[2][2];
    #pragma unroll
    for (int mt = 0; mt < 2; mt++)
      #pragma unroll
      for (int nt = 0; nt < 2; nt++) acc[mt][nt] = (f32x4){0.f,0.f,0.f,0.f};
    #pragma unroll
    for (int kt = 0; kt < 6; kt++) {
      int k = kt*32 + quad*8;
      bf16x8 Af0 = *(const bf16x8*)(Z + r0c*200 + k);
      bf16x8 Af1 = *(const bf16x8*)(Z + r1c*200 + k);
      acc[0][0] = mfma16(Af0, Bf[0][kt], acc[0][0]);
      acc[0][1] = mfma16(Af0, Bf[1][kt], acc[0][1]);
      acc[1][0] = mfma16(Af1, Bf[0][kt], acc[1][0]);
      acc[1][1] = mfma16(Af1, Bf[1][kt], acc[1][1]);
    }
    #pragma unroll
    for (int mt = 0; mt < 2; mt++) {
      if (mt == 1 && quad >= 2) break;     // rows >= 24 are garbage
      #pragma unroll
      for (int nt = 0; nt < 2; nt++) {
        int col = wv*32 + nt*16 + l15;
        int r0  = mt*16 + quad*4;
        #pragma unroll
        for (int j = 0; j < 4; j++) S1[(r0 + j)*132 + col] = acc[mt][nt][j];
      }
    }
  }
  __syncthreads();

  // ---- P4: x = LN(queries_n + attn_out) -> X bf16  (192 thr, 8/row) ----
  if (tid < 192) {
    int r = tid >> 3, p = tid & 7, w = r % 3;
    float4 v0 = *(float4*)&S1[r*132 + p*16 + 0];
    float4 v1 = *(float4*)&S1[r*132 + p*16 + 4];
    float4 v2 = *(float4*)&S1[r*132 + p*16 + 8];
    float4 v3 = *(float4*)&S1[r*132 + p*16 + 12];
    const float* qrow = QN + w*128 + p*16;
    float4 q0 = *(const float4*)(qrow + 0);
    float4 q1 = *(const float4*)(qrow + 4);
    float4 q2 = *(const float4*)(qrow + 8);
    float4 q3 = *(const float4*)(qrow + 12);
    v0.x+=q0.x; v0.y+=q0.y; v0.z+=q0.z; v0.w+=q0.w;
    v1.x+=q1.x; v1.y+=q1.y; v1.z+=q1.z; v1.w+=q1.w;
    v2.x+=q2.x; v2.y+=q2.y; v2.z+=q2.z; v2.w+=q2.w;
    v3.x+=q3.x; v3.y+=q3.y; v3.z+=q3.z; v3.w+=q3.w;
    float s1 = (v0.x+v0.y+v0.z+v0.w) + (v1.x+v1.y+v1.z+v1.w)
             + (v2.x+v2.y+v2.z+v2.w) + (v3.x+v3.y+v3.z+v3.w);
    float s2 = dot4(v0,v0) + dot4(v1,v1) + dot4(v2,v2) + dot4(v3,v3);
    #pragma unroll
    for (int o = 1; o < 8; o <<= 1) { s1 += __shfl_xor(s1, o); s2 += __shfl_xor(s2, o); }
    float m  = s1 * (1.0f/128.0f);
    float sc = rsqrtf(s2 * (1.0f/128.0f) - m*m + 1e-5f);
    float4 g0 = *(const float4*)(pag + p*16 + 0);
    float4 g1 = *(const float4*)(pag + p*16 + 4);
    float4 g2 = *(const float4*)(pag + p*16 + 8);
    float4 g3 = *(const float4*)(pag + p*16 + 12);
    float4 b0 = *(const float4*)(pab + p*16 + 0);
    float4 b1 = *(const float4*)(pab + p*16 + 4);
    float4 b2 = *(const float4*)(pab + p*16 + 8);
    float4 b3 = *(const float4*)(pab + p*16 + 12);
    uint4 pkA, pkB;
    pkA.x = pack2((v0.x-m)*sc*g0.x+b0.x, (v0.y-m)*sc*g0.y+b0.y);
    pkA.y = pack2((v0.z-m)*sc*g0.z+b0.z, (v0.w-m)*sc*g0.w+b0.w);
    pkA.z = pack2((v1.x-m)*sc*g1.x+b1.x, (v1.y-m)*sc*g1.y+b1.y);
    pkA.w = pack2((v1.z-m)*sc*g1.z+b1.z, (v1.w-m)*sc*g1.w+b1.w);
    pkB.x = pack2((v2.x-m)*sc*g2.x+b2.x, (v2.y-m)*sc*g2.y+b2.y);
    pkB.y = pack2((v2.z-m)*sc*g2.z+b2.z, (v2.w-m)*sc*g2.w+b2.w);
    pkB.z = pack2((v3.x-m)*sc*g3.x+b3.x, (v3.y-m)*sc*g3.y+b3.y);
    pkB.w = pack2((v3.z-m)*sc*g3.z+b3.z, (v3.w-m)*sc*g3.w+b3.w);
    *(uint4*)&X[r*136 + p*16]     = pkA;
    *(uint4*)&X[r*136 + p*16 + 8] = pkB;
  }
  __syncthreads();

  // ---- P5: fc1 + relu -> h1 bf16 (24x256) ----
  {
    bf16x8 Bf[4][4];
    #pragma unroll
    for (int nt = 0; nt < 4; nt++)
      #pragma unroll
      for (int kt = 0; kt < 4; kt++)
        Bf[nt][kt] = *(const bf16x8*)(W1 + (wv*64 + nt*16 + l15)*128 + kt*32 + quad*8);
    int r0c = l15;
    int r1c = min(16 + l15, 23);
    f32x4 acc[2][4];
    #pragma unroll
    for (int mt = 0; mt < 2; mt++)
      #pragma unroll
      for (int nt = 0; nt < 4; nt++) acc[mt][nt] = (f32x4){0.f,0.f,0.f,0.f};
    #pragma unroll
    for (int kt = 0; kt < 4; kt++) {
      int k = kt*32 + quad*8;
      bf16x8 Af0 = *(const bf16x8*)(X + r0c*136 + k);
      bf16x8 Af1 = *(const bf16x8*)(X + r1c*136 + k);
      #pragma unroll
      for (int nt = 0; nt < 4; nt++) {
        acc[0][nt] = mfma16(Af0, Bf[nt][kt], acc[0][nt]);
        acc[1][nt] = mfma16(Af1, Bf[nt][kt], acc[1][nt]);
      }
    }
    #pragma unroll
    for (int nt = 0; nt < 4; nt++) {
      int col = wv*64 + nt*16 + l15;
      float bb = f1b[col];
      #pragma unroll
      for (int mt = 0; mt < 2; mt++) {
        if (mt == 1 && quad >= 2) break;
        int r0 = mt*16 + quad*4;
        #pragma unroll
        for (int j = 0; j < 4; j++)
          h1[(r0 + j)*264 + col] = f2b(fmaxf(acc[mt][nt][j] + bb, 0.0f));
      }
    }
  }
  __syncthreads();

  // ---- P6: h2 = h1 @ fc2^T + b -> S1 f32 ----
  {
    bf16x8 Bf[2][8];
    #pragma unroll
    for (int nt = 0; nt < 2; nt++)
      #pragma unroll
      for (int kt = 0; kt < 8; kt++)
        Bf[nt][kt] = *(const bf16x8*)(W2 + (wv*32 + nt*16 + l15)*256 + kt*32 + quad*8);
    int r0c = l15;
    int r1c = min(16 + l15, 23);
    f32x4 acc[2][2];
    #pragma unroll
    for (int mt = 0; mt < 2; mt++)
      #pragma unroll
      for (int nt = 0; nt < 2; nt++) acc[mt][nt] = (f32x4){0.f,0.f,0.f,0.f};
    #pragma unroll
    for (int kt = 0; kt < 8; kt++) {
      int k = kt*32 + quad*8;
      bf16x8 Af0 = *(const bf16x8*)(h1 + r0c*264 + k);
      bf16x8 Af1 = *(const bf16x8*)(h1 + r1c*264 + k);
      acc[0][0] = mfma16(Af0, Bf[0][kt], acc[0][0]);
      acc[0][1] = mfma16(Af0, Bf[1][kt], acc[0][1]);
      acc[1][0] = mfma16(Af1, Bf[0][kt], acc[1][0]);
      acc[1][1] = mfma16(Af1, Bf[1][kt], acc[1][1]);
    }
    // S1 [0,12672) and h1 [12672,25344) are disjoint: no barrier needed here.
    #pragma unroll
    for (int mt = 0; mt < 2; mt++) {
      if (mt == 1 && quad >= 2) break;
      #pragma unroll
      for (int nt = 0; nt < 2; nt++) {
        int col = wv*32 + nt*16 + l15;
        float bb = f2b_[col];
        int r0 = mt*16 + quad*4;
        #pragma unroll
        for (int j = 0; j < 4; j++) S1[(r0 + j)*132 + col] = acc[mt][nt][j] + bb;
      }
    }
  }
  __syncthreads();

  // ---- P7: x2 = LN(x + h2); out = x2 @ head^T + hb  (192 thr, 8/row) ----
  if (tid < 192) {
    int r = tid >> 3, p = tid & 7;
    int e = r / 3, w = r % 3;
    float4 v0 = *(float4*)&S1[r*132 + p*16 + 0];
    float4 v1 = *(float4*)&S1[r*132 + p*16 + 4];
    float4 v2 = *(float4*)&S1[r*132 + p*16 + 8];
    float4 v3 = *(float4*)&S1[r*132 + p*16 + 12];
    uint4 u0 = *(const uint4*)&X[r*136 + p*16];
    uint4 u1 = *(const uint4*)&X[r*136 + p*16 + 8];
    v0.x += b2f(u0.x&0xffff); v0.y += b2f(u0.x>>16);
    v0.z += b2f(u0.y&0xffff); v0.w += b2f(u0.y>>16);
    v1.x += b2f(u0.z&0xffff); v1.y += b2f(u0.z>>16);
    v1.z += b2f(u0.w&0xffff); v1.w += b2f(u0.w>>16);
    v2.x += b2f(u1.x&0xffff); v2.y += b2f(u1.x>>16);
    v2.z += b2f(u1.y&0xffff); v2.w += b2f(u1.y>>16);
    v3.x += b2f(u1.z&0xffff); v3.y += b2f(u1.z>>16);
    v3.z += b2f(u1.w&0xffff); v3.w += b2f(u1.w>>16);
    float s1 = (v0.x+v0.y+v0.z+v0.w) + (v1.x+v1.y+v1.z+v1.w)
             + (v2.x+v2.y+v2.z+v2.w) + (v3.x+v3.y+v3.z+v3.w);
    float s2 = dot4(v0,v0) + dot4(v1,v1) + dot4(v2,v2) + dot4(v3,v3);
    #pragma unroll
    for (int o = 1; o < 8; o <<= 1) { s1 += __shfl_xor(s1, o); s2 += __shfl_xor(s2, o); }
    float m  = s1 * (1.0f/128.0f);
    float sc = rsqrtf(s2 * (1.0f/128.0f) - m*m + 1e-5f);
    float o0 = 0, o1 = 0;
    #pragma unroll
    for (int i = 0; i < 4; i++) {
      float4 vv = (i==0) ? v0 : (i==1) ? v1 : (i==2) ? v2 : v3;
      float4 g4 = *(const float4*)(pfg + p*16 + i*4);
      float4 b4 = *(const float4*)(pfb + p*16 + i*4);
      float4 h0 = *(const float4*)(hw + p*16 + i*4);
      float4 h8 = *(const float4*)(hw + 128 + p*16 + i*4);
      float x0 = (vv.x - m)*sc*g4.x + b4.x;
      float x1 = (vv.y - m)*sc*g4.y + b4.y;
      float x2 = (vv.z - m)*sc*g4.z + b4.z;
      float x3 = (vv.w - m)*sc*g4.w + b4.w;
      o0 = fmaf(x0,h0.x, fmaf(x1,h0.y, fmaf(x2,h0.z, fmaf(x3,h0.w, o0))));
      o1 = fmaf(x0,h8.x, fmaf(x1,h8.y, fmaf(x2,h8.z, fmaf(x3,h8.w, o1))));
    }
    #pragma unroll
    for (int o = 1; o < 8; o <<= 1) { o0 += __shfl_xor(o0, o); o1 += __shfl_xor(o1, o); }
    if (p == 0) {
      int gi = ((wg*GE + e)*3 + w)*2;
      out[gi]     = o0 + hb[0];
      out[gi + 1] = o1 + hb[1];
    }
  }
}

// ---------------------------------------------------------------------------
extern "C" void kernel_launch(void* const* d_in, const int* in_sizes, int n_in,
                              void* d_out, int out_size, void* d_ws, size_t ws_size,
                              hipStream_t stream) {
  const float* tl       = (const float*)d_in[0];
  const float* tr       = (const float*)d_in[1];
  const float* coord_w  = (const float*)d_in[2];
  const float* coord_b  = (const float*)d_in[3];
  const float* pos_emb  = (const float*)d_in[4];
  const float* side_emb = (const float*)d_in[5];
  const float* query_emb= (const float*)d_in[6];
  const float* tln_g    = (const float*)d_in[7];
  const float* tln_b    = (const float*)d_in[8];
  const float* qln_g    = (const float*)d_in[9];
  const float* qln_b    = (const float*)d_in[10];
  const float* ipw      = (const float*)d_in[11];
  const float* ipb      = (const float*)d_in[12];
  const float* opw      = (const float*)d_in[13];
  const float* opb      = (const float*)d_in[14];
  const float* f1w      = (const float*)d_in[15];
  const float* f1b      = (const float*)d_in[16];
  const float* f2w      = (const float*)d_in[17];
  const float* f2b2     = (const float*)d_in[18];
  const float* pag      = (const float*)d_in[19];
  const float* pab      = (const float*)d_in[20];
  const float* pfg      = (const float*)d_in[21];
  const float* pfb      = (const float*)d_in[22];
  const float* hw       = (const float*)d_in[23];
  const float* hb       = (const float*)d_in[24];
  char* ws = (char*)d_ws;

  k_prep<<<53, 128, 0, stream>>>(coord_w, coord_b, pos_emb, side_emb, query_emb,
                                 tln_g, tln_b, qln_g, qln_b, ipw, ipb,
                                 opw, opb, f1w, f2w, ws);
  k_main<<<32768 / GE, 256, 0, stream>>>(tl, tr, f1b, f2b2, pag, pab, pfg, pfb,
                                         hw, hb, ws, (float*)d_out);
}